// Round 5
// baseline (2310.401 us; speedup 1.0000x reference)
//
#include <hip/hip_runtime.h>
#include <math.h>

#define NN 100000
#define FIN 500
#define HIDN 64
#define KF 5
#define DORD 10
#define CHUNK 4096

typedef unsigned short ushort_t;

struct Tables { float sinc[KF][DORD+1]; float cosc[KF][DORD+1]; };

// bf16 helpers: low/high halves of a packed uint, RNE pack
__device__ inline float bl(unsigned u) { return __uint_as_float(u << 16); }
__device__ inline float bh(unsigned u) { return __uint_as_float(u & 0xffff0000u); }
__device__ inline unsigned short bf16_rne(float x) {
    unsigned u = __float_as_uint(x);
    return (unsigned short)((u + 0x7fffu + ((u >> 16) & 1u)) >> 16);
}
__device__ inline unsigned pack_bf16x2(float a, float b) {
    return (unsigned)bf16_rne(a) | ((unsigned)bf16_rne(b) << 16);
}

// ---- coeff[d] = sum_k alpha[k]*sinc[k][d] + beta[k]*cosc[k][d] ----
__global__ void coeff_kernel(const float* __restrict__ alpha, const float* __restrict__ beta,
                             Tables tb, float* __restrict__ coeff) {
    int d = threadIdx.x;
    if (d <= DORD) {
        float c = 0.f;
        #pragma unroll
        for (int k = 0; k < KF; ++k)
            c += alpha[k] * tb.sinc[k][d] + beta[k] * tb.cosc[k][d];
        coeff[d] = c;
    }
}

// ---- pass 0: dst-bucket histogram (LDS) + out-degree into 8 XCD-affine copies ----
__global__ __launch_bounds__(256) void bin_hist_kernel(
    const int* __restrict__ src, const int* __restrict__ dst,
    int* __restrict__ deg8, int* __restrict__ bucket_cnt,
    int E, int drng, int nb, int n) {
    __shared__ int h[512];
    for (int i = threadIdx.x; i < nb; i += 256) h[i] = 0;
    __syncthreads();
    int* degc = deg8 + (size_t)(blockIdx.x & 7) * n;   // blockIdx%8 ~ XCD id
    int base = blockIdx.x * CHUNK;
    int end = base + CHUNK; if (end > E) end = E;
    for (int e = base + threadIdx.x; e < end; e += 256) {
        int s = src[e], d = dst[e];
        if (s != d) {
            atomicAdd(&degc[s], 1);
            atomicAdd(&h[d / drng], 1);
        }
    }
    __syncthreads();
    for (int i = threadIdx.x; i < nb; i += 256)
        if (h[i]) atomicAdd(&bucket_cnt[i], h[i]);
}

__global__ void dinv_kernel(const int* __restrict__ deg8, float* __restrict__ dinv, int n) {
    int i = blockIdx.x * blockDim.x + threadIdx.x;
    if (i >= n) return;
    int d = 0;
    #pragma unroll
    for (int k = 0; k < 8; ++k) d += deg8[(size_t)k * n + i];
    dinv[i] = (d > 0) ? (1.0f / sqrtf((float)d)) : 0.f;
}

// ---- scan of bucket counts -> bucket_off (+cursor copy) ----
__global__ void bucket_scan_kernel(const int* __restrict__ bucket_cnt,
                                   int* __restrict__ bucket_off,
                                   int* __restrict__ bucket_cur, int nb) {
    __shared__ int tmp[512];
    int t = threadIdx.x;
    tmp[t] = (t < nb) ? bucket_cnt[t] : 0;
    __syncthreads();
    for (int off = 1; off < 512; off <<= 1) {
        int add = (t >= off) ? tmp[t - off] : 0;
        __syncthreads();
        tmp[t] += add;
        __syncthreads();
    }
    int excl = (t > 0) ? tmp[t - 1] : 0;
    if (t < nb) { bucket_off[t] = excl; bucket_cur[t] = excl; }
    if (t == nb - 1) bucket_off[nb] = tmp[t];
}

// ---- pass 1: block-local LDS binning scatter of (src,dst) pairs ----
__global__ __launch_bounds__(256) void bin_scatter_kernel(
    const int* __restrict__ src, const int* __restrict__ dst,
    int* __restrict__ bucket_cur, uint2* __restrict__ binned,
    int E, int drng, int nb) {
    __shared__ int h[512];
    for (int i = threadIdx.x; i < nb; i += 256) h[i] = 0;
    __syncthreads();
    int base = blockIdx.x * CHUNK;
    int end = base + CHUNK; if (end > E) end = E;
    for (int e = base + threadIdx.x; e < end; e += 256) {
        int s = src[e], d = dst[e];
        if (s != d) atomicAdd(&h[d / drng], 1);
    }
    __syncthreads();
    for (int i = threadIdx.x; i < nb; i += 256) {
        int c = h[i];
        h[i] = c ? atomicAdd(&bucket_cur[i], c) : 0;
    }
    __syncthreads();
    for (int e = base + threadIdx.x; e < end; e += 256) {
        int s = src[e], d = dst[e];
        if (s != d) {
            int pos = atomicAdd(&h[d / drng], 1);
            binned[pos] = make_uint2((unsigned)s, (unsigned)d);
        }
    }
}

// ---- pass 2: one block owns one bucket: local indeg, scan, row_ptr, col ----
__global__ __launch_bounds__(256) void bucket_csr_kernel(
    const uint2* __restrict__ binned, const int* __restrict__ bucket_off,
    int* __restrict__ row_ptr, int* __restrict__ col,
    int n, int drng, int nb) {
    int b = blockIdx.x;
    int e0 = bucket_off[b], e1 = bucket_off[b + 1];
    int d0 = b * drng;
    int dn = n - d0; if (dn > drng) dn = drng;
    __shared__ int ind[256];
    __shared__ int cur[256];
    int t = threadIdx.x;
    ind[t] = 0;
    __syncthreads();
    for (int e = e0 + t; e < e1; e += 256) {
        uint2 p = binned[e];
        atomicAdd(&ind[(int)p.y - d0], 1);
    }
    __syncthreads();
    for (int off = 1; off < 256; off <<= 1) {
        int add = (t >= off) ? ind[t - off] : 0;
        __syncthreads();
        ind[t] += add;
        __syncthreads();
    }
    if (t < dn) {
        int excl = (t > 0) ? ind[t - 1] : 0;
        row_ptr[d0 + t] = e0 + excl;
        cur[t] = e0 + excl;
    }
    if (b == 0 && t == 0) row_ptr[n] = bucket_off[nb];
    __syncthreads();
    for (int e = e0 + t; e < e1; e += 256) {
        uint2 p = binned[e];
        int pos = atomicAdd(&cur[(int)p.y - d0], 1);
        col[pos] = (int)p.x;
    }
}

// ---- GEMM1: H = relu(A[n,500] @ W[500,64] + b) ----
__global__ __launch_bounds__(256) void gemm1_kernel(
    const float* __restrict__ A, const float* __restrict__ W,
    const float* __restrict__ bias, float* __restrict__ H, int n) {
    __shared__ float sA[64][36];
    __shared__ float sW[32][64];
    int t = threadIdx.x;
    int tx = t & 15, ty = t >> 4;
    int rowBase = blockIdx.x * 64;
    float acc[4][4] = {{0.f}};
    for (int k0 = 0; k0 < FIN; k0 += 32) {
        #pragma unroll
        for (int l = 0; l < 2; ++l) {
            int c = t + l * 256;
            int r = c >> 3, cc = (c & 7) * 4;
            int gr = rowBase + r, gk = k0 + cc;
            float4 v = make_float4(0.f, 0.f, 0.f, 0.f);
            if (gr < n && gk < FIN) v = *(const float4*)(A + (size_t)gr * FIN + gk);
            *(float4*)&sA[r][cc] = v;
        }
        #pragma unroll
        for (int l = 0; l < 2; ++l) {
            int c = t + l * 256;
            int r = c >> 4, cc = (c & 15) * 4;
            int gk = k0 + r;
            float4 v = make_float4(0.f, 0.f, 0.f, 0.f);
            if (gk < FIN) v = *(const float4*)(W + (size_t)gk * 64 + cc);
            *(float4*)&sW[r][cc] = v;
        }
        __syncthreads();
        #pragma unroll
        for (int kk = 0; kk < 32; ++kk) {
            float a[4], b[4];
            #pragma unroll
            for (int i = 0; i < 4; ++i) a[i] = sA[ty * 4 + i][kk];
            #pragma unroll
            for (int j = 0; j < 4; ++j) b[j] = sW[kk][tx * 4 + j];
            #pragma unroll
            for (int i = 0; i < 4; ++i)
                #pragma unroll
                for (int j = 0; j < 4; ++j)
                    acc[i][j] = fmaf(a[i], b[j], acc[i][j]);
        }
        __syncthreads();
    }
    #pragma unroll
    for (int i = 0; i < 4; ++i) {
        int gr = rowBase + ty * 4 + i;
        if (gr < n) {
            float4 o;
            o.x = fmaxf(acc[i][0] + bias[tx * 4 + 0], 0.f);
            o.y = fmaxf(acc[i][1] + bias[tx * 4 + 1], 0.f);
            o.z = fmaxf(acc[i][2] + bias[tx * 4 + 2], 0.f);
            o.w = fmaxf(acc[i][3] + bias[tx * 4 + 3], 0.f);
            *(float4*)(H + (size_t)gr * 64 + tx * 4) = o;
        }
    }
}

// ---- GEMM2: X = H@W2+b2 ; out = (1+coeff[0])*X ; ty0 chunk-major bf16 ----
__global__ __launch_bounds__(256) void gemm2_kernel(
    const float* __restrict__ H, const float* __restrict__ W2,
    const float* __restrict__ b2, const float* __restrict__ coeff,
    const float* __restrict__ dinv, unsigned* __restrict__ ty0,
    float* __restrict__ out, int n) {
    __shared__ float sW[64 * 64];
    __shared__ float sb[64];
    int t = threadIdx.x;
    for (int i = t; i < 4096; i += 256) sW[i] = W2[i];
    if (t < 64) sb[t] = b2[t];
    __syncthreads();
    float c0p1 = 1.f + coeff[0];
    int lane = t & 63;
    int wid = t >> 6;
    int r0 = blockIdx.x * 128;
    int rend = r0 + 128; if (rend > n) rend = n;
    for (int r = r0 + wid; r < rend; r += 4) {
        float hv = H[(size_t)r * 64 + lane];
        float dr = dinv[r];
        float acc = sb[lane];
        #pragma unroll
        for (int k = 0; k < 64; ++k)
            acc = fmaf(__shfl(hv, k, 64), sW[k * 64 + lane], acc);
        out[(size_t)r * 64 + lane] = c0p1 * acc;
        float accn = __shfl_xor(acc, 1, 64);     // odd neighbor's value
        if (!(lane & 1)) {
            int c = lane >> 4;                    // feature chunk 0..3
            int fj = (lane & 15) >> 1;            // uint index in 32B row
            ty0[((size_t)c * n + r) * 8 + fj] = pack_bf16x2(dr * acc, dr * accn);
        }
    }
}

// ---- Chunked SpMM hop: 4 feature-chunks of 16 (3.2MB slab, L2-resident).
// chunk = blockIdx.x / bpc so chunk phases serialize within one launch.
// 8 lanes x bf16x2 per source row, 8 edges per wave-instr.
__global__ __launch_bounds__(256) void spmm_kernel(
    const int* __restrict__ row_ptr, const int* __restrict__ col,
    const float* __restrict__ dinv, const unsigned* __restrict__ tyin,
    unsigned* __restrict__ tyout, float* __restrict__ out,
    const float* __restrict__ coeff, int d, int n, int bpc, int last) {
    int blk = blockIdx.x;
    int c = blk / bpc;
    int r = (blk - c * bpc) * 4 + (threadIdx.x >> 6);
    if (r >= n) return;
    int lane = threadIdx.x & 63;
    int sub = lane >> 3;       // 0..7: edge slot
    int fj = lane & 7;         // uint (bf16x2) index within the 32B chunk-row
    const unsigned* tyc = tyin + (size_t)c * n * 8;
    int e0 = row_ptr[r], e1 = row_ptr[r + 1];
    float a0 = 0.f, a1 = 0.f;
    int e = e0 + sub;
    for (; e + 8 < e1; e += 16) {
        unsigned p0 = tyc[((size_t)col[e] << 3) + fj];
        unsigned p1 = tyc[((size_t)col[e + 8] << 3) + fj];
        a0 += bl(p0) + bl(p1);
        a1 += bh(p0) + bh(p1);
    }
    if (e < e1) {
        unsigned p = tyc[((size_t)col[e] << 3) + fj];
        a0 += bl(p); a1 += bh(p);
    }
    #pragma unroll
    for (int off = 8; off <= 32; off <<= 1) {
        a0 += __shfl_xor(a0, off, 64);
        a1 += __shfl_xor(a1, off, 64);
    }
    if (sub == 0) {
        float dr = dinv[r];
        float cd = coeff[d];
        float t0 = -dr * a0, t1 = -dr * a1;
        float* op = out + (size_t)r * 64 + c * 16 + (fj << 1);
        float2 o = *(float2*)op;
        o.x += cd * t0; o.y += cd * t1;
        *(float2*)op = o;
        if (!last)
            tyout[((size_t)c * n + r) * 8 + fj] = pack_bf16x2(dr * t0, dr * t1);
    }
}

// ---- log_softmax over rows of 64 ----
__global__ __launch_bounds__(256) void lsm_kernel(float* __restrict__ out, int n) {
    int wave = (blockIdx.x * blockDim.x + threadIdx.x) >> 6;
    int lane = threadIdx.x & 63;
    if (wave >= n) return;
    float v = out[(size_t)wave * 64 + lane];
    float m = v;
    #pragma unroll
    for (int o = 32; o; o >>= 1) m = fmaxf(m, __shfl_xor(m, o, 64));
    float ex = expf(v - m);
    float ssum = ex;
    #pragma unroll
    for (int o = 32; o; o >>= 1) ssum += __shfl_xor(ssum, o, 64);
    out[(size_t)wave * 64 + lane] = v - m - logf(ssum);
}

extern "C" void kernel_launch(void* const* d_in, const int* in_sizes, int n_in,
                              void* d_out, int out_size, void* d_ws, size_t ws_size,
                              hipStream_t stream) {
    const float* feature = (const float*)d_in[0];
    const int*   edges   = (const int*)d_in[1];
    const float* W1      = (const float*)d_in[2];
    const float* b1      = (const float*)d_in[3];
    const float* W2      = (const float*)d_in[4];
    const float* b2      = (const float*)d_in[5];
    const float* alpha   = (const float*)d_in[6];
    const float* beta    = (const float*)d_in[7];
    float* out = (float*)d_out;

    const int n = in_sizes[0] / FIN;      // 100000
    const int E = in_sizes[1] / 2;        // 3200000
    const int* src = edges;
    const int* dst = edges + E;

    const int drng = (n + 511) / 512;             // 196 dsts per bucket
    const int nb   = (n + drng - 1) / drng;       // 511 buckets

    // ---- workspace layout (256B aligned) ----
    char* ws = (char*)d_ws;
    size_t off = 0;
    auto alloc = [&](size_t bytes) { size_t o = off; off = (off + bytes + 255) & ~(size_t)255; return o; };
    float*    coeff      = (float*)   (ws + alloc(64 * 4));
    int*      deg8       = (int*)     (ws + alloc((size_t)n * 8 * 4));
    float*    dinv       = (float*)   (ws + alloc((size_t)n * 4));
    int*      row_ptr    = (int*)     (ws + alloc(((size_t)n + 1) * 4));
    int*      bucket_cnt = (int*)     (ws + alloc(512 * 4));
    int*      bucket_off = (int*)     (ws + alloc(513 * 4));
    int*      bucket_cur = (int*)     (ws + alloc(512 * 4));
    int*      col        = (int*)     (ws + alloc((size_t)E * 4));
    uint2*    binned     = (uint2*)   (ws + alloc((size_t)E * 8));
    float*    H          = (float*)   (ws + alloc((size_t)n * 64 * 4));
    unsigned* TyA        = (unsigned*)(ws + alloc((size_t)n * 32 * 4));
    unsigned* TyB        = (unsigned*)(ws + alloc((size_t)n * 32 * 4));

    // ---- host-side Taylor tables (deterministic, recomputed every call) ----
    Tables tb;
    for (int k = 0; k < KF; ++k) {
        double x = M_PI * (double)(k + 1);   // OMEGA = 1
        double p = 1.0, f = 1.0;
        for (int o = 0; o <= DORD; ++o) {
            if (o > 0) { p *= x; f *= (double)o; }
            double v = p / f;
            tb.cosc[k][o] = (o % 2 == 0) ? (float)((((o / 2) % 2 == 0) ? 1.0 : -1.0) * v) : 0.f;
            tb.sinc[k][o] = (o % 2 == 1) ? (float)(((((o - 1) / 2) % 2 == 0) ? 1.0 : -1.0) * v) : 0.f;
        }
    }

    hipMemsetAsync(deg8, 0, (size_t)n * 8 * 4, stream);
    hipMemsetAsync(bucket_cnt, 0, 512 * 4, stream);

    coeff_kernel<<<1, 64, 0, stream>>>(alpha, beta, tb, coeff);

    int nchunk = (E + CHUNK - 1) / CHUNK;
    bin_hist_kernel<<<nchunk, 256, 0, stream>>>(src, dst, deg8, bucket_cnt, E, drng, nb, n);
    dinv_kernel<<<(n + 255) / 256, 256, 0, stream>>>(deg8, dinv, n);
    bucket_scan_kernel<<<1, 512, 0, stream>>>(bucket_cnt, bucket_off, bucket_cur, nb);
    bin_scatter_kernel<<<nchunk, 256, 0, stream>>>(src, dst, bucket_cur, binned, E, drng, nb);
    bucket_csr_kernel<<<nb, 256, 0, stream>>>(binned, bucket_off, row_ptr, col, n, drng, nb);

    gemm1_kernel<<<(n + 63) / 64, 256, 0, stream>>>(feature, W1, b1, H, n);
    gemm2_kernel<<<(n + 127) / 128, 256, 0, stream>>>(H, W2, b2, coeff, dinv, TyA, out, n);

    const int bpc = (n + 3) / 4;            // blocks per feature chunk
    const unsigned* tin = TyA;
    unsigned* bufs[2] = { TyB, TyA };
    for (int d = 1; d <= DORD; ++d) {
        unsigned* tout = bufs[(d - 1) & 1];
        spmm_kernel<<<bpc * 4, 256, 0, stream>>>(row_ptr, col, dinv, tin, tout, out,
                                                 coeff, d, n, bpc, d == DORD ? 1 : 0);
        tin = tout;
    }
    lsm_kernel<<<(n + 3) / 4, 256, 0, stream>>>(out, n);
}